// Round 4
// baseline (336.577 us; speedup 1.0000x reference)
//
#include <hip/hip_runtime.h>
#include <hip/hip_bf16.h>

#define B_ 4
#define S_ 2048
#define H_ 8
#define E_ 64
#define NW 4      // waves per attention block
#define QB 16     // q rows per wave
#define KT 64     // k/v tile size
#define NT (S_ / KT)

typedef __attribute__((ext_vector_type(8))) short bf16x8v;
typedef __attribute__((ext_vector_type(4))) float f32x4v;

static __device__ __forceinline__ unsigned short f2bf(float f) {
    __hip_bfloat16 h = __float2bfloat16(f);
    return *reinterpret_cast<unsigned short*>(&h);
}

// ---------------------------------------------------------------------------
// Projection: q = (x@Wq + bq) * 0.125*log2e -> bf16 [B,H,S,E]   (exp2 domain)
//             k = (x@Wk + bk)               -> bf16 [B,H,S,E]
//             v = (x@Wv + bv)               -> bf16 [B,H,E,S]   (pre-transposed)
// grid = B * S/16, block = 192 (wave 0: Q, wave 1: K, wave 2: V)
// ---------------------------------------------------------------------------
__global__ __launch_bounds__(192)
void proj_kernel(const float* __restrict__ query, const float* __restrict__ key,
                 const float* __restrict__ value,
                 const float* __restrict__ Wq, const float* __restrict__ bq,
                 const float* __restrict__ Wk, const float* __restrict__ bk,
                 const float* __restrict__ Wv, const float* __restrict__ bv,
                 __hip_bfloat16* __restrict__ qp, __hip_bfloat16* __restrict__ kp,
                 __hip_bfloat16* __restrict__ vtp)
{
    const int tid  = threadIdx.x;
    const int wave = tid >> 6;
    const int lane = tid & 63;
    const int lr   = lane & 15;
    const int lh   = lane >> 4;
    const int ntile = S_ / 16;
    const int b     = blockIdx.x / ntile;
    const int sbase = (blockIdx.x % ntile) * 16;

    const float* x    = (wave == 0) ? query : (wave == 1) ? key : value;
    const float* W    = (wave == 0) ? Wq    : (wave == 1) ? Wk  : Wv;
    const float* bias = (wave == 0) ? bq    : (wave == 1) ? bk  : bv;

    bf16x8v wf[4][2];
#pragma unroll
    for (int cb = 0; cb < 4; ++cb)
#pragma unroll
        for (int hf = 0; hf < 2; ++hf)
#pragma unroll
            for (int j = 0; j < 8; ++j) {
                int e = lh * 8 + j + 32 * hf;
                wf[cb][hf][j] = (short)f2bf(W[e * E_ + cb * 16 + lr]);
            }
    float bvals[4];
#pragma unroll
    for (int cb = 0; cb < 4; ++cb) bvals[cb] = bias[cb * 16 + lr];

    // 0.125 (1/sqrt E) * log2(e): attn softmax runs in exp2 domain
    const float QSCALE = 0.18033688011112042f;

    for (int h = 0; h < H_; ++h) {
        const float* xrow = x + (((size_t)b * S_ + sbase + lr) * H_ + h) * E_;
        const float4* xr = reinterpret_cast<const float4*>(xrow);
        float4 a0 = xr[lh * 2], a1 = xr[lh * 2 + 1];
        float4 a2 = xr[8 + lh * 2], a3 = xr[8 + lh * 2 + 1];
        bf16x8v af[2];
        af[0][0] = (short)f2bf(a0.x); af[0][1] = (short)f2bf(a0.y);
        af[0][2] = (short)f2bf(a0.z); af[0][3] = (short)f2bf(a0.w);
        af[0][4] = (short)f2bf(a1.x); af[0][5] = (short)f2bf(a1.y);
        af[0][6] = (short)f2bf(a1.z); af[0][7] = (short)f2bf(a1.w);
        af[1][0] = (short)f2bf(a2.x); af[1][1] = (short)f2bf(a2.y);
        af[1][2] = (short)f2bf(a2.z); af[1][3] = (short)f2bf(a2.w);
        af[1][4] = (short)f2bf(a3.x); af[1][5] = (short)f2bf(a3.y);
        af[1][6] = (short)f2bf(a3.z); af[1][7] = (short)f2bf(a3.w);

#pragma unroll
        for (int cb = 0; cb < 4; ++cb) {
            f32x4v acc = {0.f, 0.f, 0.f, 0.f};
            acc = __builtin_amdgcn_mfma_f32_16x16x32_bf16(af[0], wf[cb][0], acc, 0, 0, 0);
            acc = __builtin_amdgcn_mfma_f32_16x16x32_bf16(af[1], wf[cb][1], acc, 0, 0, 0);
#pragma unroll
            for (int r = 0; r < 4; ++r) {
                float v  = acc[r] + bvals[cb];
                int row  = sbase + 4 * lh + r;
                int col  = cb * 16 + lr;
                if (wave == 0) {
                    v *= QSCALE;
                    qp[(((size_t)b * H_ + h) * S_ + row) * E_ + col] = __float2bfloat16(v);
                } else if (wave == 1) {
                    kp[(((size_t)b * H_ + h) * S_ + row) * E_ + col] = __float2bfloat16(v);
                } else {
                    vtp[(((size_t)b * H_ + h) * E_ + col) * S_ + row] = __float2bfloat16(v);
                }
            }
        }
    }
}

// ---------------------------------------------------------------------------
// Flash attention. ALL vmem loads are plain C++ (compiler-tracked -> its
// counted vmcnt waits are exact). Pipeline structure:
//   top:    issue K/V tile t+1 loads (regs) + mask tile t+1 loads (regs)
//   middle: QK^T, online softmax (exp2), P->LDS, PV with mask t
//   bottom: ds_write staged regs to other buffer; lgkmcnt(0); raw s_barrier
// Loads stay in flight across the whole middle; no vmcnt(0) drain anywhere.
// grid = B*H * S/(QB*NW) = 1024, block = 256
// ---------------------------------------------------------------------------
__global__ __launch_bounds__(256, 4)
void attn_kernel(const __hip_bfloat16* __restrict__ qp,
                 const __hip_bfloat16* __restrict__ kp,
                 const __hip_bfloat16* __restrict__ vtp,
                 const int* __restrict__ mask,
                 float* __restrict__ out)
{
    __shared__ unsigned short Kt[2][KT * E_];    // swizzled [k][e], dbuf
    __shared__ unsigned short Vs[2][KT * E_];    // swizzled [e][k], dbuf
    __shared__ unsigned short Pt[NW][16 * KT];   // swizzled [q][k], per wave

    const int tid  = threadIdx.x;
    const int wave = tid >> 6;
    const int lane = tid & 63;
    const int lr   = lane & 15;
    const int lh   = lane >> 4;

    // XCD-bijective swizzle: grid 1024 = 8 chunks of 128 -> each XCD gets
    // 4 consecutive (b,h) heads; their K/V (0.5 MB each) stay L2-resident.
    const int bid = blockIdx.x;
    const int swz = (bid & 7) * 128 + (bid >> 3);
    const int bh  = swz >> 5;
    const int qt  = swz & 31;
    const int qbase = qt * (QB * NW) + wave * QB;

    const __hip_bfloat16* qrow = qp + ((size_t)bh * S_ + qbase + lr) * E_;
    bf16x8v aq0 = *reinterpret_cast<const bf16x8v*>(qrow + lh * 8);
    bf16x8v aq1 = *reinterpret_cast<const bf16x8v*>(qrow + lh * 8 + 32);

    float m_[4], lsum[4];
    f32x4v Oa[4];
#pragma unroll
    for (int r = 0; r < 4; ++r) { m_[r] = -INFINITY; lsum[r] = 0.f; }
#pragma unroll
    for (int eb = 0; eb < 4; ++eb) Oa[eb] = {0.f, 0.f, 0.f, 0.f};

    const char* kgb = (const char*)(kp  + (size_t)bh * S_ * E_);
    const char* vgb = (const char*)(vtp + (size_t)bh * E_ * S_);
    const int*  mlane = mask + ((size_t)bh * S_ + qbase + lr) * S_ + lh * 8;

    // staging geometry: 512 16B-chunks; thread handles chunks tid and tid+256.
    const int rA = tid >> 3;          // row 0..31 (chunk A); chunk B row = rA+32
    const int cA = tid & 7;           // 16B column chunk
    const int gkA = rA * 128 + cA * 16;            // K: + kb*128
    const int gkB = gkA + 32 * 128;
    const int gvA = rA * (S_ * 2) + cA * 16;       // V: + kb*2
    const int gvB = gvA + 32 * (S_ * 2);
    const int wS  = ((rA & 7) << 4);               // same for rows rA and rA+32
    const int wA  = (rA * 128 + cA * 16) ^ wS;
    const int wB  = ((rA + 32) * 128 + cA * 16) ^ wS;

    char* Kt0 = (char*)(Kt[0]); char* Kt1 = (char*)(Kt[1]);
    char* Vs0 = (char*)(Vs[0]); char* Vs1 = (char*)(Vs[1]);
    char* PtB = (char*)(Pt[wave]);

    int4 mc0, mc1, mc2, mc3;   // mask for current tile

    // ---- prologue: stage tile 0 into buf0; load mask tile 0
    {
        int4 a0 = *reinterpret_cast<const int4*>(kgb + gkA);
        int4 a1 = *reinterpret_cast<const int4*>(kgb + gkB);
        int4 b0 = *reinterpret_cast<const int4*>(vgb + gvA);
        int4 b1 = *reinterpret_cast<const int4*>(vgb + gvB);
        mc0 = *reinterpret_cast<const int4*>(mlane);
        mc1 = *reinterpret_cast<const int4*>(mlane + 4);
        mc2 = *reinterpret_cast<const int4*>(mlane + 32);
        mc3 = *reinterpret_cast<const int4*>(mlane + 36);
        *reinterpret_cast<int4*>(Kt0 + wA) = a0;
        *reinterpret_cast<int4*>(Kt0 + wB) = a1;
        *reinterpret_cast<int4*>(Vs0 + wA) = b0;
        *reinterpret_cast<int4*>(Vs0 + wB) = b1;
    }
    asm volatile("s_waitcnt lgkmcnt(0)" ::: "memory");
    __builtin_amdgcn_s_barrier();
    __builtin_amdgcn_sched_barrier(0);

    for (int kt = 0; kt < NT; ++kt) {
        const int kb = kt * KT;
        char* KtC = (kt & 1) ? Kt1 : Kt0;
        char* VsC = (kt & 1) ? Vs1 : Vs0;
        char* KtN = (kt & 1) ? Kt0 : Kt1;
        char* VsN = (kt & 1) ? Vs0 : Vs1;
        const bool pref = (kt + 1 < NT);

        // ---- issue next tile's loads (stay in flight across the compute)
        int4 sk0, sk1, sv0, sv1, mn0, mn1, mn2, mn3;
        if (pref) {
            const char* kq = kgb + (size_t)(kb + KT) * 128;
            const char* vq = vgb + (size_t)(kb + KT) * 2;
            sk0 = *reinterpret_cast<const int4*>(kq + gkA);
            sk1 = *reinterpret_cast<const int4*>(kq + gkB);
            sv0 = *reinterpret_cast<const int4*>(vq + gvA);
            sv1 = *reinterpret_cast<const int4*>(vq + gvB);
            const int* mp = mlane + kb + KT;
            mn0 = *reinterpret_cast<const int4*>(mp);
            mn1 = *reinterpret_cast<const int4*>(mp + 4);
            mn2 = *reinterpret_cast<const int4*>(mp + 32);
            mn3 = *reinterpret_cast<const int4*>(mp + 36);
        }
        __builtin_amdgcn_sched_barrier(0);  // pin load issue above compute

        // ---- QK^T : D layout row = 4*lh+r (q), col = lr (k within cb)
        f32x4v sc[4];
        __builtin_amdgcn_s_setprio(1);
#pragma unroll
        for (int cb = 0; cb < 4; ++cb) {
            int kcol = cb * 16 + lr;
            bf16x8v bk0 = *reinterpret_cast<bf16x8v*>(
                KtC + ((kcol * 128 + lh * 16) ^ ((kcol & 7) << 4)));
            bf16x8v bk1 = *reinterpret_cast<bf16x8v*>(
                KtC + ((kcol * 128 + 64 + lh * 16) ^ ((kcol & 7) << 4)));
            f32x4v a = {0.f, 0.f, 0.f, 0.f};
            a = __builtin_amdgcn_mfma_f32_16x16x32_bf16(aq0, bk0, a, 0, 0, 0);
            a = __builtin_amdgcn_mfma_f32_16x16x32_bf16(aq1, bk1, a, 0, 0, 0);
            sc[cb] = a;
        }
        __builtin_amdgcn_s_setprio(0);

        // ---- online softmax in exp2 domain; write raw P (bf16) to LDS
#pragma unroll
        for (int r = 0; r < 4; ++r) {
            float tmax = fmaxf(fmaxf(sc[0][r], sc[1][r]), fmaxf(sc[2][r], sc[3][r]));
#pragma unroll
            for (int off = 1; off < 16; off <<= 1)
                tmax = fmaxf(tmax, __shfl_xor(tmax, off));
            float newm  = fmaxf(m_[r], tmax);
            float scale = __builtin_amdgcn_exp2f(m_[r] - newm);
            m_[r] = newm;
            int q = 4 * lh + r;
            float rs = 0.f;
#pragma unroll
            for (int cb = 0; cb < 4; ++cb) {
                float pv = __builtin_amdgcn_exp2f(sc[cb][r] - newm);
                rs += pv;
                *reinterpret_cast<unsigned short*>(
                    PtB + ((q * 128 + (cb * 16 + lr) * 2) ^ ((q & 7) << 4))) = f2bf(pv);
            }
#pragma unroll
            for (int off = 1; off < 16; off <<= 1)
                rs += __shfl_xor(rs, off);
            lsum[r] = lsum[r] * scale + rs;
#pragma unroll
            for (int eb = 0; eb < 4; ++eb) Oa[eb][r] *= scale;
        }

        // ---- PV with dropout applied on the A-fragment (8 consecutive k/lane)
        __builtin_amdgcn_s_setprio(1);
#pragma unroll
        for (int mh = 0; mh < 2; ++mh) {
            int k0 = mh * 32 + lh * 8;
            bf16x8v pa = *reinterpret_cast<bf16x8v*>(
                PtB + ((lr * 128 + k0 * 2) ^ ((lr & 7) << 4)));
            int4 ma = (mh == 0) ? mc0 : mc2;
            int4 mb = (mh == 0) ? mc1 : mc3;
            pa[0] = ma.x ? pa[0] : (short)0;
            pa[1] = ma.y ? pa[1] : (short)0;
            pa[2] = ma.z ? pa[2] : (short)0;
            pa[3] = ma.w ? pa[3] : (short)0;
            pa[4] = mb.x ? pa[4] : (short)0;
            pa[5] = mb.y ? pa[5] : (short)0;
            pa[6] = mb.z ? pa[6] : (short)0;
            pa[7] = mb.w ? pa[7] : (short)0;
#pragma unroll
            for (int eb = 0; eb < 4; ++eb) {
                int e = eb * 16 + lr;
                bf16x8v vb = *reinterpret_cast<bf16x8v*>(
                    VsC + ((e * 128 + k0 * 2) ^ ((e & 7) << 4)));
                Oa[eb] = __builtin_amdgcn_mfma_f32_16x16x32_bf16(pa, vb, Oa[eb], 0, 0, 0);
            }
        }
        __builtin_amdgcn_s_setprio(0);

        // ---- land staged regs into the other buffer; tile boundary
        if (pref) {
            *reinterpret_cast<int4*>(KtN + wA) = sk0;
            *reinterpret_cast<int4*>(KtN + wB) = sk1;
            *reinterpret_cast<int4*>(VsN + wA) = sv0;
            *reinterpret_cast<int4*>(VsN + wB) = sv1;
            mc0 = mn0; mc1 = mn1; mc2 = mn2; mc3 = mn3;
        }
        asm volatile("s_waitcnt lgkmcnt(0)" ::: "memory");
        __builtin_amdgcn_s_barrier();
        __builtin_amdgcn_sched_barrier(0);
    }

    // ---- epilogue: out = O * (1/0.9) / lsum   (fp32, [B,H,S,E])
    constexpr float KEEP_INV = 1.0f / 0.9f;
    float* orow = out + ((size_t)bh * S_ + qbase) * E_;
#pragma unroll
    for (int r = 0; r < 4; ++r) {
        float inv = KEEP_INV / lsum[r];
        int q = 4 * lh + r;
#pragma unroll
        for (int eb = 0; eb < 4; ++eb)
            orow[(size_t)q * E_ + eb * 16 + lr] = Oa[eb][r] * inv;
    }
}

extern "C" void kernel_launch(void* const* d_in, const int* in_sizes, int n_in,
                              void* d_out, int out_size, void* d_ws, size_t ws_size,
                              hipStream_t stream) {
    (void)in_sizes; (void)n_in; (void)out_size; (void)ws_size;
    const float* query = (const float*)d_in[0];
    const float* key   = (const float*)d_in[1];
    const float* value = (const float*)d_in[2];
    const float* Wq    = (const float*)d_in[3];
    const float* bq    = (const float*)d_in[4];
    const float* Wk    = (const float*)d_in[5];
    const float* bk    = (const float*)d_in[6];
    const float* Wv    = (const float*)d_in[7];
    const float* bv    = (const float*)d_in[8];
    const int*   mask  = (const int*)d_in[9];
    float*       out   = (float*)d_out;

    const size_t per = (size_t)B_ * H_ * S_ * E_;
    __hip_bfloat16* qp  = (__hip_bfloat16*)d_ws;
    __hip_bfloat16* kp  = qp + per;
    __hip_bfloat16* vtp = kp + per;

    proj_kernel<<<B_ * (S_ / 16), 192, 0, stream>>>(query, key, value,
                                                    Wq, bq, Wk, bk, Wv, bv,
                                                    qp, kp, vtp);
    attn_kernel<<<B_ * H_ * (S_ / (QB * NW)), 256, 0, stream>>>(qp, kp, vtp, mask, out);
}

// Round 5
// 328.671 us; speedup vs baseline: 1.0241x; 1.0241x over previous
//
#include <hip/hip_runtime.h>
#include <hip/hip_bf16.h>

#define B_ 4
#define S_ 2048
#define H_ 8
#define E_ 64
#define NW 4      // waves per attention block
#define QB 16     // q rows per wave
#define KT 64     // k/v tile size
#define NT (S_ / KT)

typedef __attribute__((ext_vector_type(8))) short bf16x8v;
typedef __attribute__((ext_vector_type(4))) float f32x4v;

static __device__ __forceinline__ unsigned short f2bf(float f) {
    __hip_bfloat16 h = __float2bfloat16(f);
    return *reinterpret_cast<unsigned short*>(&h);
}

// async global->LDS DMA, 16B/lane; side-effecting intrinsic -> cannot be sunk
static __device__ __forceinline__ void gl_lds16(const void* g, void* lds) {
    __builtin_amdgcn_global_load_lds(
        (const __attribute__((address_space(1))) unsigned int*)g,
        (__attribute__((address_space(3))) unsigned int*)lds, 16, 0, 0);
}

// ---------------------------------------------------------------------------
// Projection: q = (x@Wq + bq) * 0.125*log2e -> bf16 [B,H,S,E]   (exp2 domain)
//             k = (x@Wk + bk)               -> bf16 [B,H,S,E]
//             v = (x@Wv + bv)               -> bf16 [B,H,E,S]   (pre-transposed)
// grid = B * S/16, block = 192 (wave 0: Q, wave 1: K, wave 2: V)
// ---------------------------------------------------------------------------
__global__ __launch_bounds__(192)
void proj_kernel(const float* __restrict__ query, const float* __restrict__ key,
                 const float* __restrict__ value,
                 const float* __restrict__ Wq, const float* __restrict__ bq,
                 const float* __restrict__ Wk, const float* __restrict__ bk,
                 const float* __restrict__ Wv, const float* __restrict__ bv,
                 __hip_bfloat16* __restrict__ qp, __hip_bfloat16* __restrict__ kp,
                 __hip_bfloat16* __restrict__ vtp)
{
    const int tid  = threadIdx.x;
    const int wave = tid >> 6;
    const int lane = tid & 63;
    const int lr   = lane & 15;
    const int lh   = lane >> 4;
    const int ntile = S_ / 16;
    const int b     = blockIdx.x / ntile;
    const int sbase = (blockIdx.x % ntile) * 16;

    const float* x    = (wave == 0) ? query : (wave == 1) ? key : value;
    const float* W    = (wave == 0) ? Wq    : (wave == 1) ? Wk  : Wv;
    const float* bias = (wave == 0) ? bq    : (wave == 1) ? bk  : bv;

    bf16x8v wf[4][2];
#pragma unroll
    for (int cb = 0; cb < 4; ++cb)
#pragma unroll
        for (int hf = 0; hf < 2; ++hf)
#pragma unroll
            for (int j = 0; j < 8; ++j) {
                int e = lh * 8 + j + 32 * hf;
                wf[cb][hf][j] = (short)f2bf(W[e * E_ + cb * 16 + lr]);
            }
    float bvals[4];
#pragma unroll
    for (int cb = 0; cb < 4; ++cb) bvals[cb] = bias[cb * 16 + lr];

    // 0.125 (1/sqrt E) * log2(e): attn softmax runs in exp2 domain
    const float QSCALE = 0.18033688011112042f;

    for (int h = 0; h < H_; ++h) {
        const float* xrow = x + (((size_t)b * S_ + sbase + lr) * H_ + h) * E_;
        const float4* xr = reinterpret_cast<const float4*>(xrow);
        float4 a0 = xr[lh * 2], a1 = xr[lh * 2 + 1];
        float4 a2 = xr[8 + lh * 2], a3 = xr[8 + lh * 2 + 1];
        bf16x8v af[2];
        af[0][0] = (short)f2bf(a0.x); af[0][1] = (short)f2bf(a0.y);
        af[0][2] = (short)f2bf(a0.z); af[0][3] = (short)f2bf(a0.w);
        af[0][4] = (short)f2bf(a1.x); af[0][5] = (short)f2bf(a1.y);
        af[0][6] = (short)f2bf(a1.z); af[0][7] = (short)f2bf(a1.w);
        af[1][0] = (short)f2bf(a2.x); af[1][1] = (short)f2bf(a2.y);
        af[1][2] = (short)f2bf(a2.z); af[1][3] = (short)f2bf(a2.w);
        af[1][4] = (short)f2bf(a3.x); af[1][5] = (short)f2bf(a3.y);
        af[1][6] = (short)f2bf(a3.z); af[1][7] = (short)f2bf(a3.w);

#pragma unroll
        for (int cb = 0; cb < 4; ++cb) {
            f32x4v acc = {0.f, 0.f, 0.f, 0.f};
            acc = __builtin_amdgcn_mfma_f32_16x16x32_bf16(af[0], wf[cb][0], acc, 0, 0, 0);
            acc = __builtin_amdgcn_mfma_f32_16x16x32_bf16(af[1], wf[cb][1], acc, 0, 0, 0);
#pragma unroll
            for (int r = 0; r < 4; ++r) {
                float v  = acc[r] + bvals[cb];
                int row  = sbase + 4 * lh + r;
                int col  = cb * 16 + lr;
                if (wave == 0) {
                    v *= QSCALE;
                    qp[(((size_t)b * H_ + h) * S_ + row) * E_ + col] = __float2bfloat16(v);
                } else if (wave == 1) {
                    kp[(((size_t)b * H_ + h) * S_ + row) * E_ + col] = __float2bfloat16(v);
                } else {
                    vtp[(((size_t)b * H_ + h) * E_ + col) * S_ + row] = __float2bfloat16(v);
                }
            }
        }
    }
}

// ---------------------------------------------------------------------------
// Flash attention, counted-boundary pipeline:
//   top:    4x global_load_lds (tile t+1, OLDEST vmem; pinned by sched_barrier)
//           4x plain int4 mask loads (tile t+1; compiler-tracked)
//   middle: QK^T, online softmax (exp2), P->LDS, PV with mask t
//   bottom: s_waitcnt vmcnt(4)  (staging landed; mask stays in flight)
//           s_barrier
// Mask regs alternate A/B via 2x unroll (no copies -> no forced drain).
// grid = B*H * S/(QB*NW) = 1024, block = 256
// ---------------------------------------------------------------------------
struct SOff { unsigned kA, kB, vA, vB; int lo; };

template<bool PREF>
static __device__ __forceinline__ void tile_phase(
    int kt, const char* kgb, const char* vgb, const int* mlane,
    char* KtC, char* VsC, char* KtN, char* VsN, SOff so,
    int4& c0, int4& c1, int4& c2, int4& c3,      // mask for THIS tile
    int4& n0, int4& n1, int4& n2, int4& n3,      // mask regs for NEXT tile
    bf16x8v aq0, bf16x8v aq1, char* PtB, int lr, int lh,
    float (&m_)[4], float (&lsum)[4], f32x4v (&Oa)[4])
{
    if constexpr (PREF) {
        // staging FIRST: must remain the 4 oldest vmem ops for vmcnt(4)
        const unsigned kadd = (unsigned)(kt + 1) * (KT * E_ * 2);
        const unsigned vadd = (unsigned)(kt + 1) * (KT * 2);
        gl_lds16(kgb + kadd + so.kA, KtN + so.lo);
        gl_lds16(kgb + kadd + so.kB, KtN + so.lo + 1024);
        gl_lds16(vgb + vadd + so.vA, VsN + so.lo);
        gl_lds16(vgb + vadd + so.vB, VsN + so.lo + 1024);
    }
    __builtin_amdgcn_sched_barrier(0);
    if constexpr (PREF) {
        const int* mp = mlane + (kt + 1) * KT;
        n0 = *reinterpret_cast<const int4*>(mp);
        n1 = *reinterpret_cast<const int4*>(mp + 4);
        n2 = *reinterpret_cast<const int4*>(mp + 32);
        n3 = *reinterpret_cast<const int4*>(mp + 36);
    }
    __builtin_amdgcn_sched_barrier(0);

    // ---- QK^T : D layout row = 4*lh+r (q), col = lr (k within cb)
    f32x4v sc[4];
    __builtin_amdgcn_s_setprio(1);
#pragma unroll
    for (int cb = 0; cb < 4; ++cb) {
        int kcol = cb * 16 + lr;
        bf16x8v bk0 = *reinterpret_cast<bf16x8v*>(
            KtC + ((kcol * 128 + lh * 16) ^ ((kcol & 7) << 4)));
        bf16x8v bk1 = *reinterpret_cast<bf16x8v*>(
            KtC + ((kcol * 128 + 64 + lh * 16) ^ ((kcol & 7) << 4)));
        f32x4v a = {0.f, 0.f, 0.f, 0.f};
        a = __builtin_amdgcn_mfma_f32_16x16x32_bf16(aq0, bk0, a, 0, 0, 0);
        a = __builtin_amdgcn_mfma_f32_16x16x32_bf16(aq1, bk1, a, 0, 0, 0);
        sc[cb] = a;
    }
    __builtin_amdgcn_s_setprio(0);

    // ---- online softmax in exp2 domain; write raw P (bf16) to LDS
#pragma unroll
    for (int r = 0; r < 4; ++r) {
        float tmax = fmaxf(fmaxf(sc[0][r], sc[1][r]), fmaxf(sc[2][r], sc[3][r]));
#pragma unroll
        for (int off = 1; off < 16; off <<= 1)
            tmax = fmaxf(tmax, __shfl_xor(tmax, off));
        float newm  = fmaxf(m_[r], tmax);
        float scale = __builtin_amdgcn_exp2f(m_[r] - newm);
        m_[r] = newm;
        int q = 4 * lh + r;
        float rs = 0.f;
#pragma unroll
        for (int cb = 0; cb < 4; ++cb) {
            float pv = __builtin_amdgcn_exp2f(sc[cb][r] - newm);
            rs += pv;
            *reinterpret_cast<unsigned short*>(
                PtB + ((q * 128 + (cb * 16 + lr) * 2) ^ ((q & 7) << 4))) = f2bf(pv);
        }
#pragma unroll
        for (int off = 1; off < 16; off <<= 1)
            rs += __shfl_xor(rs, off);
        lsum[r] = lsum[r] * scale + rs;
#pragma unroll
        for (int eb = 0; eb < 4; ++eb) Oa[eb][r] *= scale;
    }

    // ---- PV with dropout applied on the A-fragment (8 consecutive k/lane)
    __builtin_amdgcn_s_setprio(1);
#pragma unroll
    for (int mh = 0; mh < 2; ++mh) {
        int k0 = mh * 32 + lh * 8;
        bf16x8v pa = *reinterpret_cast<bf16x8v*>(
            PtB + ((lr * 128 + k0 * 2) ^ ((lr & 7) << 4)));
        int4 ma = (mh == 0) ? c0 : c2;
        int4 mb = (mh == 0) ? c1 : c3;
        pa[0] = ma.x ? pa[0] : (short)0;
        pa[1] = ma.y ? pa[1] : (short)0;
        pa[2] = ma.z ? pa[2] : (short)0;
        pa[3] = ma.w ? pa[3] : (short)0;
        pa[4] = mb.x ? pa[4] : (short)0;
        pa[5] = mb.y ? pa[5] : (short)0;
        pa[6] = mb.z ? pa[6] : (short)0;
        pa[7] = mb.w ? pa[7] : (short)0;
#pragma unroll
        for (int eb = 0; eb < 4; ++eb) {
            int e = eb * 16 + lr;
            bf16x8v vb = *reinterpret_cast<bf16x8v*>(
                VsC + ((e * 128 + k0 * 2) ^ ((e & 7) << 4)));
            Oa[eb] = __builtin_amdgcn_mfma_f32_16x16x32_bf16(pa, vb, Oa[eb], 0, 0, 0);
        }
    }
    __builtin_amdgcn_s_setprio(0);

    if constexpr (PREF) {
        // staging (4 oldest) landed; this tile's 4 mask loads stay in flight
        asm volatile("s_waitcnt vmcnt(4)" ::: "memory");
        __builtin_amdgcn_s_barrier();
        __builtin_amdgcn_sched_barrier(0);
    }
}

__global__ __launch_bounds__(256, 4)
void attn_kernel(const __hip_bfloat16* __restrict__ qp,
                 const __hip_bfloat16* __restrict__ kp,
                 const __hip_bfloat16* __restrict__ vtp,
                 const int* __restrict__ mask,
                 float* __restrict__ out)
{
    __shared__ unsigned short Kt[2][KT * E_];    // swizzled [k][e], dbuf
    __shared__ unsigned short Vs[2][KT * E_];    // swizzled [e][k], dbuf
    __shared__ unsigned short Pt[NW][16 * KT];   // swizzled [q][k], per wave

    const int tid  = threadIdx.x;
    const int wave = tid >> 6;
    const int lane = tid & 63;
    const int lr   = lane & 15;
    const int lh   = lane >> 4;

    // XCD-bijective swizzle: grid 1024 = 8 chunks of 128 -> each XCD gets
    // 4 consecutive (b,h) heads; their K/V (0.5 MB each) stay L2-resident.
    const int bid = blockIdx.x;
    const int swz = (bid & 7) * 128 + (bid >> 3);
    const int bh  = swz >> 5;
    const int qt  = swz & 31;
    const int qbase = qt * (QB * NW) + wave * QB;

    const __hip_bfloat16* qrow = qp + ((size_t)bh * S_ + qbase + lr) * E_;
    bf16x8v aq0 = *reinterpret_cast<const bf16x8v*>(qrow + lh * 8);
    bf16x8v aq1 = *reinterpret_cast<const bf16x8v*>(qrow + lh * 8 + 32);

    float m_[4], lsum[4];
    f32x4v Oa[4];
#pragma unroll
    for (int r = 0; r < 4; ++r) { m_[r] = -INFINITY; lsum[r] = 0.f; }
#pragma unroll
    for (int eb = 0; eb < 4; ++eb) Oa[eb] = {0.f, 0.f, 0.f, 0.f};

    const char* kgb = (const char*)(kp  + (size_t)bh * S_ * E_);
    const char* vgb = (const char*)(vtp + (size_t)bh * E_ * S_);
    const int*  mlane = mask + ((size_t)bh * S_ + qbase + lr) * S_ + lh * 8;

    // staging: wave w stages rows [w*16, w*16+16); linear LDS dest, source
    // column pre-XOR'd so the LDS image matches the read-side swizzle
    const int rowA = wave * 16 + (lane >> 3);
    const int rowB = rowA + 8;
    const int e2   = (((lane & 7) ^ (lane >> 3)) << 4);
    SOff so;
    so.kA = (unsigned)rowA * 128 + e2;
    so.kB = (unsigned)rowB * 128 + e2;
    so.vA = (unsigned)rowA * (S_ * 2) + e2;
    so.vB = (unsigned)rowB * (S_ * 2) + e2;
    so.lo = wave * 2048;

    char* Kt0 = (char*)(Kt[0]); char* Kt1 = (char*)(Kt[1]);
    char* Vs0 = (char*)(Vs[0]); char* Vs1 = (char*)(Vs[1]);
    char* PtB = (char*)(Pt[wave]);

    int4 mA0, mA1, mA2, mA3, mB0, mB1, mB2, mB3;

    // ---- prologue: stage tile 0 -> buf0 (oldest 4 vmem); mask tile 0 -> mA
    gl_lds16(kgb + so.kA, Kt0 + so.lo);
    gl_lds16(kgb + so.kB, Kt0 + so.lo + 1024);
    gl_lds16(vgb + so.vA, Vs0 + so.lo);
    gl_lds16(vgb + so.vB, Vs0 + so.lo + 1024);
    __builtin_amdgcn_sched_barrier(0);
    mA0 = *reinterpret_cast<const int4*>(mlane);
    mA1 = *reinterpret_cast<const int4*>(mlane + 4);
    mA2 = *reinterpret_cast<const int4*>(mlane + 32);
    mA3 = *reinterpret_cast<const int4*>(mlane + 36);
    __builtin_amdgcn_sched_barrier(0);
    asm volatile("s_waitcnt vmcnt(4)" ::: "memory");
    __builtin_amdgcn_s_barrier();
    __builtin_amdgcn_sched_barrier(0);

    for (int j = 0; j < 15; ++j) {
        tile_phase<true>(2 * j,     kgb, vgb, mlane, Kt0, Vs0, Kt1, Vs1, so,
                         mA0, mA1, mA2, mA3, mB0, mB1, mB2, mB3,
                         aq0, aq1, PtB, lr, lh, m_, lsum, Oa);
        tile_phase<true>(2 * j + 1, kgb, vgb, mlane, Kt1, Vs1, Kt0, Vs0, so,
                         mB0, mB1, mB2, mB3, mA0, mA1, mA2, mA3,
                         aq0, aq1, PtB, lr, lh, m_, lsum, Oa);
    }
    tile_phase<true>(30,  kgb, vgb, mlane, Kt0, Vs0, Kt1, Vs1, so,
                     mA0, mA1, mA2, mA3, mB0, mB1, mB2, mB3,
                     aq0, aq1, PtB, lr, lh, m_, lsum, Oa);
    tile_phase<false>(31, kgb, vgb, mlane, Kt1, Vs1, Kt0, Vs0, so,
                      mB0, mB1, mB2, mB3, mA0, mA1, mA2, mA3,
                      aq0, aq1, PtB, lr, lh, m_, lsum, Oa);

    // ---- epilogue: out = O * (1/0.9) / lsum   (fp32, [B,H,S,E])
    constexpr float KEEP_INV = 1.0f / 0.9f;
    float* orow = out + ((size_t)bh * S_ + qbase) * E_;
#pragma unroll
    for (int r = 0; r < 4; ++r) {
        float inv = KEEP_INV / lsum[r];
        int q = 4 * lh + r;
#pragma unroll
        for (int eb = 0; eb < 4; ++eb)
            orow[(size_t)q * E_ + eb * 16 + lr] = Oa[eb][r] * inv;
    }
}

extern "C" void kernel_launch(void* const* d_in, const int* in_sizes, int n_in,
                              void* d_out, int out_size, void* d_ws, size_t ws_size,
                              hipStream_t stream) {
    (void)in_sizes; (void)n_in; (void)out_size; (void)ws_size;
    const float* query = (const float*)d_in[0];
    const float* key   = (const float*)d_in[1];
    const float* value = (const float*)d_in[2];
    const float* Wq    = (const float*)d_in[3];
    const float* bq    = (const float*)d_in[4];
    const float* Wk    = (const float*)d_in[5];
    const float* bk    = (const float*)d_in[6];
    const float* Wv    = (const float*)d_in[7];
    const float* bv    = (const float*)d_in[8];
    const int*   mask  = (const int*)d_in[9];
    float*       out   = (float*)d_out;

    const size_t per = (size_t)B_ * H_ * S_ * E_;
    __hip_bfloat16* qp  = (__hip_bfloat16*)d_ws;
    __hip_bfloat16* kp  = qp + per;
    __hip_bfloat16* vtp = kp + per;

    proj_kernel<<<B_ * (S_ / 16), 192, 0, stream>>>(query, key, value,
                                                    Wq, bq, Wk, bk, Wv, bv,
                                                    qp, kp, vtp);
    attn_kernel<<<B_ * H_ * (S_ / (QB * NW)), 256, 0, stream>>>(qp, kp, vtp, mask, out);
}